// Round 1
// baseline (671.455 us; speedup 1.0000x reference)
//
#include <hip/hip_runtime.h>

#define DIM 256
#define DOUT 64

// ---------------- utility kernels ----------------

__global__ void copy_f32x4(const float4* __restrict__ src, float4* __restrict__ dst, int n4) {
    int i = blockIdx.x * blockDim.x + threadIdx.x;
    int stride = gridDim.x * blockDim.x;
    for (; i < n4; i += stride) dst[i] = src[i];
}

__global__ void copy_i32(const int* __restrict__ src, int* __restrict__ dst, int n) {
    int i = blockIdx.x * blockDim.x + threadIdx.x;
    if (i < n) dst[i] = src[i];
}

// ---------------- CSR build ----------------

__global__ void hist_kernel(const int* __restrict__ dst, int* __restrict__ deg, int E) {
    int i = blockIdx.x * blockDim.x + threadIdx.x;
    if (i < E) atomicAdd(&deg[dst[i]], 1);
}

// exclusive scan of deg[0..n-1] -> row_ptr[0..n], single block of 256 threads
__global__ void scan_kernel(const int* __restrict__ deg, int* __restrict__ row_ptr, int n) {
    __shared__ int sums[256];
    int t = threadIdx.x;
    int chunk = (n + 255) / 256;
    int lo = t * chunk;
    int hi = min(lo + chunk, n);
    int s = 0;
    for (int i = lo; i < hi; ++i) s += deg[i];
    sums[t] = s;
    __syncthreads();
    for (int off = 1; off < 256; off <<= 1) {
        int v = (t >= off) ? sums[t - off] : 0;
        __syncthreads();
        sums[t] += v;
        __syncthreads();
    }
    int excl = (t == 0) ? 0 : sums[t - 1];
    int run = excl;
    for (int i = lo; i < hi; ++i) { row_ptr[i] = run; run += deg[i]; }
    if (t == 255) row_ptr[n] = run;   // == E
}

__global__ void scatter_kernel(const int* __restrict__ src, const int* __restrict__ dst,
                               int* __restrict__ cursor, int* __restrict__ perm, int E) {
    int i = blockIdx.x * blockDim.x + threadIdx.x;
    if (i < E) {
        int d = dst[i];
        int p = atomicAdd(&cursor[d], 1);
        perm[p] = src[i];
    }
}

// ---------------- aggregation: z = h + sum_{e: dst=n} h[src[e]] ----------------
// one 64-lane wave per node, float4 per lane (64*16B = 1KB row)
__global__ void agg_kernel(const float4* __restrict__ h4, const int* __restrict__ row_ptr,
                           const int* __restrict__ perm, float4* __restrict__ z4, int n) {
    int wave = threadIdx.x >> 6;
    int lane = threadIdx.x & 63;
    int node = blockIdx.x * 4 + wave;
    if (node >= n) return;
    float4 acc = h4[(size_t)node * 64 + lane];
    int lo = row_ptr[node], hi = row_ptr[node + 1];
    for (int e = lo; e < hi; ++e) {
        int s = perm[e];
        float4 v = h4[(size_t)s * 64 + lane];
        acc.x += v.x; acc.y += v.y; acc.z += v.z; acc.w += v.w;
    }
    z4[(size_t)node * 64 + lane] = acc;
}

// ---------------- f32 tiled GEMM: C[M,256] = act(A[M,256] @ W[256,256] + bias) ----------------
// BM=64, BN=64, BK=16; 256 threads; each thread computes 4x4
template <bool RELU>
__global__ __launch_bounds__(256) void gemm_kernel(const float* __restrict__ A,
                                                   const float* __restrict__ W,
                                                   const float* __restrict__ bias,
                                                   float* __restrict__ C, int M) {
    __shared__ float As[16][64];   // As[k][m]
    __shared__ float Bs[16][64];   // Bs[k][j]
    const int tid = threadIdx.x;
    const int by = blockIdx.x;     // row tile
    const int bx = blockIdx.y;     // col tile (0..3)
    const int tx = tid & 15;
    const int ty = tid >> 4;
    const int m0 = by * 64;
    const int j0 = bx * 64;

    // A-load: row = tid>>2 (0..63), k offset = (tid&3)*4
    const int la_r = tid >> 2;
    const int la_k = (tid & 3) * 4;
    // B-load: row = tid>>4 (0..15), col = (tid&15)*4
    const int lb_r = tid >> 4;
    const int lb_c = (tid & 15) * 4;

    float acc[4][4] = {};

    for (int kt = 0; kt < 256; kt += 16) {
        float4 av = make_float4(0.f, 0.f, 0.f, 0.f);
        int am = m0 + la_r;
        if (am < M) av = *reinterpret_cast<const float4*>(&A[(size_t)am * 256 + kt + la_k]);
        As[la_k + 0][la_r] = av.x;
        As[la_k + 1][la_r] = av.y;
        As[la_k + 2][la_r] = av.z;
        As[la_k + 3][la_r] = av.w;
        *reinterpret_cast<float4*>(&Bs[lb_r][lb_c]) =
            *reinterpret_cast<const float4*>(&W[(size_t)(kt + lb_r) * 256 + j0 + lb_c]);
        __syncthreads();
#pragma unroll
        for (int kk = 0; kk < 16; ++kk) {
            float a[4], b[4];
            *reinterpret_cast<float4*>(a) = *reinterpret_cast<const float4*>(&As[kk][ty * 4]);
            *reinterpret_cast<float4*>(b) = *reinterpret_cast<const float4*>(&Bs[kk][tx * 4]);
#pragma unroll
            for (int i = 0; i < 4; ++i)
#pragma unroll
                for (int j = 0; j < 4; ++j)
                    acc[i][j] += a[i] * b[j];
        }
        __syncthreads();
    }

#pragma unroll
    for (int i = 0; i < 4; ++i) {
        int m = m0 + ty * 4 + i;
        if (m >= M) continue;
        float tmp[4];
#pragma unroll
        for (int j = 0; j < 4; ++j) {
            float v = acc[i][j] + bias[j0 + tx * 4 + j];
            if (RELU) v = fmaxf(v, 0.f);
            tmp[j] = v;
        }
        *reinterpret_cast<float4*>(&C[(size_t)m * 256 + j0 + tx * 4]) =
            *reinterpret_cast<const float4*>(tmp);
    }
}

// ---------------- pooling ----------------

__global__ void gstart_kernel(const int* __restrict__ bids, int* __restrict__ gstart,
                              int n, int G) {
    int g = blockIdx.x * blockDim.x + threadIdx.x;
    if (g > G) return;
    if (g == G) { gstart[G] = n; return; }
    int lo = 0, hi = n;
    while (lo < hi) {
        int mid = (lo + hi) >> 1;
        if (bids[mid] < g) lo = mid + 1; else hi = mid;
    }
    gstart[g] = lo;
}

__global__ void pool_kernel(const float* __restrict__ h, const int* __restrict__ gstart,
                            float* __restrict__ pooled) {
    int g = blockIdx.x;
    int d = threadIdx.x;     // 256
    float acc = 0.f;
    int lo = gstart[g], hi = gstart[g + 1];
    for (int nd = lo; nd < hi; ++nd) acc += h[(size_t)nd * DIM + d];
    pooled[(size_t)g * DIM + d] = acc;
}

__global__ void out_kernel(const float* __restrict__ pooled, const float* __restrict__ Wout,
                           const float* __restrict__ bout, float* __restrict__ out) {
    __shared__ float p[DIM];
    int g = blockIdx.x;
    for (int d = threadIdx.x; d < DIM; d += blockDim.x) p[d] = pooled[(size_t)g * DIM + d];
    __syncthreads();
    int o = threadIdx.x;
    if (o < DOUT) {
        float acc = bout[o];
        for (int d = 0; d < DIM; ++d) acc += p[d] * Wout[(size_t)d * DOUT + o];
        out[(size_t)g * DOUT + o] = acc;
    }
}

// ---------------- launch ----------------

extern "C" void kernel_launch(void* const* d_in, const int* in_sizes, int n_in,
                              void* d_out, int out_size, void* d_ws, size_t ws_size,
                              hipStream_t stream) {
    const float* x    = (const float*)d_in[0];
    const int*   esrc = (const int*)d_in[1];
    const int*   edst = (const int*)d_in[2];
    const int*   bids = (const int*)d_in[3];
    const float* W1   = (const float*)d_in[4];
    const float* b1   = (const float*)d_in[5];
    const float* W2   = (const float*)d_in[6];
    const float* b2   = (const float*)d_in[7];
    const float* Wout = (const float*)d_in[8];
    const float* bout = (const float*)d_in[9];

    const int N = in_sizes[3];            // 20000
    const int E = in_sizes[1];            // 320000
    const int L = in_sizes[5] / DIM;      // 4
    const int G = out_size / (DOUT + DIM);// 128

    char* ws = (char*)d_ws;
    size_t off = 0;
    auto carve = [&](size_t bytes) -> char* {
        char* p = ws + off;
        off = (off + bytes + 255) & ~(size_t)255;
        return p;
    };
    int*   row_ptr = (int*)carve((size_t)(N + 1) * sizeof(int));
    int*   cursor  = (int*)carve((size_t)N * sizeof(int));
    int*   perm    = (int*)carve((size_t)E * sizeof(int));
    int*   gstart  = (int*)carve((size_t)(G + 1) * sizeof(int));
    float* h       = (float*)carve((size_t)N * DIM * sizeof(float));
    float* z       = (float*)carve((size_t)N * DIM * sizeof(float));
    float* t       = (float*)carve((size_t)N * DIM * sizeof(float));
    (void)ws_size;

    // h = x
    copy_f32x4<<<2048, 256, 0, stream>>>((const float4*)x, (float4*)h, N * (DIM / 4));

    // CSR build: cursor as degree scratch
    hipMemsetAsync(cursor, 0, (size_t)N * sizeof(int), stream);
    hist_kernel<<<(E + 255) / 256, 256, 0, stream>>>(edst, cursor, E);
    scan_kernel<<<1, 256, 0, stream>>>(cursor, row_ptr, N);
    copy_i32<<<(N + 255) / 256, 256, 0, stream>>>(row_ptr, cursor, N);
    scatter_kernel<<<(E + 255) / 256, 256, 0, stream>>>(esrc, edst, cursor, perm, E);

    dim3 ggrid((N + 63) / 64, 4);
    for (int l = 0; l < L; ++l) {
        agg_kernel<<<(N + 3) / 4, 256, 0, stream>>>((const float4*)h, row_ptr, perm,
                                                    (float4*)z, N);
        gemm_kernel<true><<<ggrid, 256, 0, stream>>>(
            z, W1 + (size_t)l * DIM * DIM, b1 + (size_t)l * DIM, t, N);
        if (l < L - 1)
            gemm_kernel<true><<<ggrid, 256, 0, stream>>>(
                t, W2 + (size_t)l * DIM * DIM, b2 + (size_t)l * DIM, h, N);
        else
            gemm_kernel<false><<<ggrid, 256, 0, stream>>>(
                t, W2 + (size_t)l * DIM * DIM, b2 + (size_t)l * DIM, h, N);
    }

    float* outp   = (float*)d_out;
    float* pooled = outp + (size_t)G * DOUT;
    gstart_kernel<<<1, 256, 0, stream>>>(bids, gstart, N, G);
    pool_kernel<<<G, DIM, 0, stream>>>(h, gstart, pooled);
    out_kernel<<<G, 64, 0, stream>>>(pooled, Wout, bout, outp);
}

// Round 2
// 433.480 us; speedup vs baseline: 1.5490x; 1.5490x over previous
//
#include <hip/hip_runtime.h>

#define DIM 256
#define DOUT 64

typedef short bf16x8 __attribute__((ext_vector_type(8)));
typedef float f32x4 __attribute__((ext_vector_type(4)));

// ---- bf16 helpers (bit-level, RNE) ----
static __device__ __forceinline__ float b2f(unsigned short u) {
    return __uint_as_float(((unsigned)u) << 16);
}
static __device__ __forceinline__ unsigned short f2bf(float f) {
    unsigned u = __float_as_uint(f);
    unsigned r = (u + 0x7fffu + ((u >> 16) & 1u)) >> 16;
    return (unsigned short)r;
}

// ---------------- convert x (f32) -> h (bf16) ----------------
__global__ void cvt_f32_bf16(const float4* __restrict__ src, ushort4* __restrict__ dst, int n4) {
    int i = blockIdx.x * blockDim.x + threadIdx.x;
    int stride = gridDim.x * blockDim.x;
    for (; i < n4; i += stride) {
        float4 v = src[i];
        ushort4 o;
        o.x = f2bf(v.x); o.y = f2bf(v.y); o.z = f2bf(v.z); o.w = f2bf(v.w);
        dst[i] = o;
    }
}

__global__ void copy_i32(const int* __restrict__ src, int* __restrict__ dst, int n) {
    int i = blockIdx.x * blockDim.x + threadIdx.x;
    if (i < n) dst[i] = src[i];
}

// ---------------- CSR build ----------------
__global__ void hist_kernel(const int* __restrict__ dst, int* __restrict__ deg, int E) {
    int i = blockIdx.x * blockDim.x + threadIdx.x;
    if (i < E) atomicAdd(&deg[dst[i]], 1);
}

__global__ void scan_kernel(const int* __restrict__ deg, int* __restrict__ row_ptr, int n) {
    __shared__ int sums[256];
    int t = threadIdx.x;
    int chunk = (n + 255) / 256;
    int lo = t * chunk;
    int hi = min(lo + chunk, n);
    int s = 0;
    for (int i = lo; i < hi; ++i) s += deg[i];
    sums[t] = s;
    __syncthreads();
    for (int off = 1; off < 256; off <<= 1) {
        int v = (t >= off) ? sums[t - off] : 0;
        __syncthreads();
        sums[t] += v;
        __syncthreads();
    }
    int excl = (t == 0) ? 0 : sums[t - 1];
    int run = excl;
    for (int i = lo; i < hi; ++i) { row_ptr[i] = run; run += deg[i]; }
    if (t == 255) row_ptr[n] = run;
}

__global__ void scatter_kernel(const int* __restrict__ src, const int* __restrict__ dst,
                               int* __restrict__ cursor, int* __restrict__ perm, int E) {
    int i = blockIdx.x * blockDim.x + threadIdx.x;
    if (i < E) {
        int d = dst[i];
        int p = atomicAdd(&cursor[d], 1);
        perm[p] = src[i];
    }
}

// ---------------- transpose + convert W [K][N] f32 -> Wt [N][K] bf16 ----------------
__global__ void transpose_w(const float* __restrict__ W, unsigned short* __restrict__ Wt) {
    __shared__ float tile[32][33];
    int l = blockIdx.z;
    int k0 = blockIdx.x * 32, n0 = blockIdx.y * 32;
    const float* Wl = W + (size_t)l * DIM * DIM;
    unsigned short* Wtl = Wt + (size_t)l * DIM * DIM;
    int tx = threadIdx.x, ty = threadIdx.y;
    for (int i = ty; i < 32; i += 8)
        tile[i][tx] = Wl[(size_t)(k0 + i) * DIM + n0 + tx];
    __syncthreads();
    for (int i = ty; i < 32; i += 8)
        Wtl[(size_t)(n0 + i) * DIM + k0 + tx] = f2bf(tile[tx][i]);
}

// ---------------- aggregation (bf16): z = h + sum_{e: dst=n} h[src[e]] ----------------
// one wave per node; 64 lanes x 8B (ushort4) = 512B row
__global__ void agg_kernel(const ushort4* __restrict__ h4, const int* __restrict__ row_ptr,
                           const int* __restrict__ perm, ushort4* __restrict__ z4, int n) {
    int wave = threadIdx.x >> 6;
    int lane = threadIdx.x & 63;
    int node = blockIdx.x * 4 + wave;
    if (node >= n) return;
    size_t base = (size_t)node * 64 + lane;
    ushort4 hv = h4[base];
    float ax = b2f(hv.x), ay = b2f(hv.y), az = b2f(hv.z), aw = b2f(hv.w);
    int lo = row_ptr[node], hi = row_ptr[node + 1];
    int e = lo;
    for (; e + 2 <= hi; e += 2) {
        int s0 = perm[e], s1 = perm[e + 1];
        ushort4 v0 = h4[(size_t)s0 * 64 + lane];
        ushort4 v1 = h4[(size_t)s1 * 64 + lane];
        ax += b2f(v0.x) + b2f(v1.x);
        ay += b2f(v0.y) + b2f(v1.y);
        az += b2f(v0.z) + b2f(v1.z);
        aw += b2f(v0.w) + b2f(v1.w);
    }
    if (e < hi) {
        int s0 = perm[e];
        ushort4 v0 = h4[(size_t)s0 * 64 + lane];
        ax += b2f(v0.x); ay += b2f(v0.y); az += b2f(v0.z); aw += b2f(v0.w);
    }
    ushort4 o;
    o.x = f2bf(ax); o.y = f2bf(ay); o.z = f2bf(az); o.w = f2bf(aw);
    z4[base] = o;
}

// ---------------- bf16 MFMA GEMM: C[M,256] = act(A[M,256] @ W + bias) ----------------
// A bf16 row-major [M][256]; Bt bf16 [256 cols][256 k] (= W transposed); C bf16.
// Block 256 thr = 4 waves (2x2); BM=128, BN=64; per wave 64x32 via 4x2 16x16x32 frags.
template <bool RELU>
__global__ __launch_bounds__(256) void mfma_gemm(const unsigned short* __restrict__ A,
                                                 const unsigned short* __restrict__ Bt,
                                                 const float* __restrict__ bias,
                                                 unsigned short* __restrict__ C, int M) {
    const int tid = threadIdx.x;
    const int wave = tid >> 6;
    const int lane = tid & 63;
    const int wr = wave >> 1;            // 0..1
    const int wc = wave & 1;             // 0..1
    const int l15 = lane & 15;
    const int lk8 = (lane >> 4) * 8;     // 0,8,16,24
    const int m_base = blockIdx.x * 128 + wr * 64;
    const int n_base = blockIdx.y * 64 + wc * 32;

    f32x4 acc[4][2] = {};

    for (int kb = 0; kb < 256; kb += 32) {
        bf16x8 a[4], b[2];
#pragma unroll
        for (int m = 0; m < 4; ++m) {
            int r = m_base + m * 16 + l15;
            r = min(r, M - 1);
            a[m] = *reinterpret_cast<const bf16x8*>(&A[(size_t)r * 256 + kb + lk8]);
        }
#pragma unroll
        for (int n = 0; n < 2; ++n) {
            int c = n_base + n * 16 + l15;
            b[n] = *reinterpret_cast<const bf16x8*>(&Bt[(size_t)c * 256 + kb + lk8]);
        }
#pragma unroll
        for (int m = 0; m < 4; ++m)
#pragma unroll
            for (int n = 0; n < 2; ++n)
                acc[m][n] = __builtin_amdgcn_mfma_f32_16x16x32_bf16(a[m], b[n], acc[m][n], 0, 0, 0);
    }

    // C/D layout: col = lane&15, row = (lane>>4)*4 + reg
#pragma unroll
    for (int n = 0; n < 2; ++n) {
        int col = n_base + n * 16 + l15;
        float bv = bias[col];
#pragma unroll
        for (int m = 0; m < 4; ++m) {
#pragma unroll
            for (int r = 0; r < 4; ++r) {
                int row = m_base + m * 16 + (lane >> 4) * 4 + r;
                if (row < M) {
                    float v = acc[m][n][r] + bv;
                    if (RELU) v = fmaxf(v, 0.f);
                    C[(size_t)row * 256 + col] = f2bf(v);
                }
            }
        }
    }
}

// ---------------- pooling ----------------
__global__ void gstart_kernel(const int* __restrict__ bids, int* __restrict__ gstart,
                              int n, int G) {
    int g = blockIdx.x * blockDim.x + threadIdx.x;
    if (g > G) return;
    if (g == G) { gstart[G] = n; return; }
    int lo = 0, hi = n;
    while (lo < hi) {
        int mid = (lo + hi) >> 1;
        if (bids[mid] < g) lo = mid + 1; else hi = mid;
    }
    gstart[g] = lo;
}

__global__ void pool_kernel(const unsigned short* __restrict__ h, const int* __restrict__ gstart,
                            float* __restrict__ pooled) {
    int g = blockIdx.x;
    int d = threadIdx.x;     // 256
    float acc = 0.f;
    int lo = gstart[g], hi = gstart[g + 1];
    for (int nd = lo; nd < hi; ++nd) acc += b2f(h[(size_t)nd * DIM + d]);
    pooled[(size_t)g * DIM + d] = acc;
}

__global__ void out_kernel(const float* __restrict__ pooled, const float* __restrict__ Wout,
                           const float* __restrict__ bout, float* __restrict__ out) {
    __shared__ float p[DIM];
    int g = blockIdx.x;
    for (int d = threadIdx.x; d < DIM; d += blockDim.x) p[d] = pooled[(size_t)g * DIM + d];
    __syncthreads();
    int o = threadIdx.x;
    if (o < DOUT) {
        float acc = bout[o];
        for (int d = 0; d < DIM; ++d) acc += p[d] * Wout[(size_t)d * DOUT + o];
        out[(size_t)g * DOUT + o] = acc;
    }
}

// ---------------- launch ----------------
extern "C" void kernel_launch(void* const* d_in, const int* in_sizes, int n_in,
                              void* d_out, int out_size, void* d_ws, size_t ws_size,
                              hipStream_t stream) {
    const float* x    = (const float*)d_in[0];
    const int*   esrc = (const int*)d_in[1];
    const int*   edst = (const int*)d_in[2];
    const int*   bids = (const int*)d_in[3];
    const float* W1   = (const float*)d_in[4];
    const float* b1   = (const float*)d_in[5];
    const float* W2   = (const float*)d_in[6];
    const float* b2   = (const float*)d_in[7];
    const float* Wout = (const float*)d_in[8];
    const float* bout = (const float*)d_in[9];

    const int N = in_sizes[3];             // 20000
    const int E = in_sizes[1];             // 320000
    const int L = in_sizes[5] / DIM;       // 4
    const int G = out_size / (DOUT + DIM); // 128

    char* ws = (char*)d_ws;
    size_t off = 0;
    auto carve = [&](size_t bytes) -> char* {
        char* p = ws + off;
        off = (off + bytes + 255) & ~(size_t)255;
        return p;
    };
    int* row_ptr = (int*)carve((size_t)(N + 1) * sizeof(int));
    int* cursor  = (int*)carve((size_t)N * sizeof(int));
    int* perm    = (int*)carve((size_t)E * sizeof(int));
    int* gstart  = (int*)carve((size_t)(G + 1) * sizeof(int));
    unsigned short* h   = (unsigned short*)carve((size_t)N * DIM * 2);
    unsigned short* z   = (unsigned short*)carve((size_t)N * DIM * 2);
    unsigned short* t   = (unsigned short*)carve((size_t)N * DIM * 2);
    unsigned short* wt1 = (unsigned short*)carve((size_t)L * DIM * DIM * 2);
    unsigned short* wt2 = (unsigned short*)carve((size_t)L * DIM * DIM * 2);
    (void)ws_size;

    // h = bf16(x)
    cvt_f32_bf16<<<2048, 256, 0, stream>>>((const float4*)x, (ushort4*)h, N * (DIM / 4));

    // CSR build (cursor doubles as degree scratch)
    hipMemsetAsync(cursor, 0, (size_t)N * sizeof(int), stream);
    hist_kernel<<<(E + 255) / 256, 256, 0, stream>>>(edst, cursor, E);
    scan_kernel<<<1, 256, 0, stream>>>(cursor, row_ptr, N);
    copy_i32<<<(N + 255) / 256, 256, 0, stream>>>(row_ptr, cursor, N);
    scatter_kernel<<<(E + 255) / 256, 256, 0, stream>>>(esrc, edst, cursor, perm, E);

    // Wt = bf16(W^T) for both MLP weight sets
    {
        dim3 tgrid(DIM / 32, DIM / 32, L);
        dim3 tblk(32, 8);
        transpose_w<<<tgrid, tblk, 0, stream>>>(W1, wt1);
        transpose_w<<<tgrid, tblk, 0, stream>>>(W2, wt2);
    }

    dim3 ggrid((N + 127) / 128, 4);
    for (int l = 0; l < L; ++l) {
        agg_kernel<<<(N + 3) / 4, 256, 0, stream>>>((const ushort4*)h, row_ptr, perm,
                                                    (ushort4*)z, N);
        mfma_gemm<true><<<ggrid, 256, 0, stream>>>(
            z, wt1 + (size_t)l * DIM * DIM, b1 + (size_t)l * DIM, t, N);
        if (l < L - 1)
            mfma_gemm<true><<<ggrid, 256, 0, stream>>>(
                t, wt2 + (size_t)l * DIM * DIM, b2 + (size_t)l * DIM, h, N);
        else
            mfma_gemm<false><<<ggrid, 256, 0, stream>>>(
                t, wt2 + (size_t)l * DIM * DIM, b2 + (size_t)l * DIM, h, N);
    }

    float* outp   = (float*)d_out;
    float* pooled = outp + (size_t)G * DOUT;
    gstart_kernel<<<1, 256, 0, stream>>>(bids, gstart, N, G);
    pool_kernel<<<G, DIM, 0, stream>>>(h, gstart, pooled);
    out_kernel<<<G, 64, 0, stream>>>(pooled, Wout, bout, outp);
}

// Round 3
// 385.378 us; speedup vs baseline: 1.7423x; 1.1248x over previous
//
#include <hip/hip_runtime.h>

#define DIM 256
#define DOUT 64
#define PSPLITS 16

typedef short bf16x8 __attribute__((ext_vector_type(8)));
typedef float f32x4 __attribute__((ext_vector_type(4)));

// ---- bf16 helpers (bit-level, RNE) ----
static __device__ __forceinline__ float b2f(unsigned short u) {
    return __uint_as_float(((unsigned)u) << 16);
}
static __device__ __forceinline__ unsigned short f2bf(float f) {
    unsigned u = __float_as_uint(f);
    unsigned r = (u + 0x7fffu + ((u >> 16) & 1u)) >> 16;
    return (unsigned short)r;
}

// ---------------- convert x (f32) -> h (bf16) ----------------
__global__ void cvt_f32_bf16(const float4* __restrict__ src, ushort4* __restrict__ dst, int n4) {
    int i = blockIdx.x * blockDim.x + threadIdx.x;
    int stride = gridDim.x * blockDim.x;
    for (; i < n4; i += stride) {
        float4 v = src[i];
        ushort4 o;
        o.x = f2bf(v.x); o.y = f2bf(v.y); o.z = f2bf(v.z); o.w = f2bf(v.w);
        dst[i] = o;
    }
}

__global__ void copy_i32(const int* __restrict__ src, int* __restrict__ dst, int n) {
    int i = blockIdx.x * blockDim.x + threadIdx.x;
    if (i < n) dst[i] = src[i];
}

// ---------------- CSR build ----------------
__global__ void hist_kernel(const int* __restrict__ dst, int* __restrict__ deg, int E) {
    int i = blockIdx.x * blockDim.x + threadIdx.x;
    if (i < E) atomicAdd(&deg[dst[i]], 1);
}

__global__ void scan_kernel(const int* __restrict__ deg, int* __restrict__ row_ptr, int n) {
    __shared__ int sums[256];
    int t = threadIdx.x;
    int chunk = (n + 255) / 256;
    int lo = t * chunk;
    int hi = min(lo + chunk, n);
    int s = 0;
    for (int i = lo; i < hi; ++i) s += deg[i];
    sums[t] = s;
    __syncthreads();
    for (int off = 1; off < 256; off <<= 1) {
        int v = (t >= off) ? sums[t - off] : 0;
        __syncthreads();
        sums[t] += v;
        __syncthreads();
    }
    int excl = (t == 0) ? 0 : sums[t - 1];
    int run = excl;
    for (int i = lo; i < hi; ++i) { row_ptr[i] = run; run += deg[i]; }
    if (t == 255) row_ptr[n] = run;
}

__global__ void scatter_kernel(const int* __restrict__ src, const int* __restrict__ dst,
                               int* __restrict__ cursor, int* __restrict__ perm, int E) {
    int i = blockIdx.x * blockDim.x + threadIdx.x;
    if (i < E) {
        int d = dst[i];
        int p = atomicAdd(&cursor[d], 1);
        perm[p] = src[i];
    }
}

// ---------------- transpose + convert W [K][N] f32 -> Wt [N][K] bf16 ----------------
__global__ void transpose_w(const float* __restrict__ W, unsigned short* __restrict__ Wt) {
    __shared__ float tile[32][33];
    int l = blockIdx.z;
    int k0 = blockIdx.x * 32, n0 = blockIdx.y * 32;
    const float* Wl = W + (size_t)l * DIM * DIM;
    unsigned short* Wtl = Wt + (size_t)l * DIM * DIM;
    int tx = threadIdx.x, ty = threadIdx.y;
    for (int i = ty; i < 32; i += 8)
        tile[i][tx] = Wl[(size_t)(k0 + i) * DIM + n0 + tx];
    __syncthreads();
    for (int i = ty; i < 32; i += 8)
        Wtl[(size_t)(n0 + i) * DIM + k0 + tx] = f2bf(tile[tx][i]);
}

// ---------------- aggregation (bf16): z = h + sum_{e: dst=n} h[src[e]] ----------------
// one wave per node; 64 lanes x 8B (ushort4) = 512B row; 4-deep gather pipeline
__global__ void agg_kernel(const ushort4* __restrict__ h4, const int* __restrict__ row_ptr,
                           const int* __restrict__ perm, ushort4* __restrict__ z4, int n) {
    int wave = threadIdx.x >> 6;
    int lane = threadIdx.x & 63;
    int node = blockIdx.x * 4 + wave;
    if (node >= n) return;
    size_t base = (size_t)node * 64 + lane;
    ushort4 hv = h4[base];
    float ax = b2f(hv.x), ay = b2f(hv.y), az = b2f(hv.z), aw = b2f(hv.w);
    int lo = row_ptr[node], hi = row_ptr[node + 1];
    int e = lo;
    for (; e + 4 <= hi; e += 4) {
        int s0 = perm[e], s1 = perm[e + 1], s2 = perm[e + 2], s3 = perm[e + 3];
        ushort4 v0 = h4[(size_t)s0 * 64 + lane];
        ushort4 v1 = h4[(size_t)s1 * 64 + lane];
        ushort4 v2 = h4[(size_t)s2 * 64 + lane];
        ushort4 v3 = h4[(size_t)s3 * 64 + lane];
        ax += b2f(v0.x) + b2f(v1.x) + b2f(v2.x) + b2f(v3.x);
        ay += b2f(v0.y) + b2f(v1.y) + b2f(v2.y) + b2f(v3.y);
        az += b2f(v0.z) + b2f(v1.z) + b2f(v2.z) + b2f(v3.z);
        aw += b2f(v0.w) + b2f(v1.w) + b2f(v2.w) + b2f(v3.w);
    }
    for (; e < hi; ++e) {
        int s0 = perm[e];
        ushort4 v0 = h4[(size_t)s0 * 64 + lane];
        ax += b2f(v0.x); ay += b2f(v0.y); az += b2f(v0.z); aw += b2f(v0.w);
    }
    ushort4 o;
    o.x = f2bf(ax); o.y = f2bf(ay); o.z = f2bf(az); o.w = f2bf(aw);
    z4[base] = o;
}

// ---------------- bf16 MFMA GEMM: C[M,256] = act(A[M,256] @ W + bias) ----------------
template <bool RELU>
__global__ __launch_bounds__(256) void mfma_gemm(const unsigned short* __restrict__ A,
                                                 const unsigned short* __restrict__ Bt,
                                                 const float* __restrict__ bias,
                                                 unsigned short* __restrict__ C, int M) {
    const int tid = threadIdx.x;
    const int wave = tid >> 6;
    const int lane = tid & 63;
    const int wr = wave >> 1;            // 0..1
    const int wc = wave & 1;             // 0..1
    const int l15 = lane & 15;
    const int lk8 = (lane >> 4) * 8;     // 0,8,16,24
    const int m_base = blockIdx.x * 128 + wr * 64;
    const int n_base = blockIdx.y * 64 + wc * 32;

    f32x4 acc[4][2] = {};

    for (int kb = 0; kb < 256; kb += 32) {
        bf16x8 a[4], b[2];
#pragma unroll
        for (int m = 0; m < 4; ++m) {
            int r = m_base + m * 16 + l15;
            r = min(r, M - 1);
            a[m] = *reinterpret_cast<const bf16x8*>(&A[(size_t)r * 256 + kb + lk8]);
        }
#pragma unroll
        for (int n = 0; n < 2; ++n) {
            int c = n_base + n * 16 + l15;
            b[n] = *reinterpret_cast<const bf16x8*>(&Bt[(size_t)c * 256 + kb + lk8]);
        }
#pragma unroll
        for (int m = 0; m < 4; ++m)
#pragma unroll
            for (int n = 0; n < 2; ++n)
                acc[m][n] = __builtin_amdgcn_mfma_f32_16x16x32_bf16(a[m], b[n], acc[m][n], 0, 0, 0);
    }

    // C/D layout: col = lane&15, row = (lane>>4)*4 + reg
#pragma unroll
    for (int n = 0; n < 2; ++n) {
        int col = n_base + n * 16 + l15;
        float bv = bias[col];
#pragma unroll
        for (int m = 0; m < 4; ++m) {
#pragma unroll
            for (int r = 0; r < 4; ++r) {
                int row = m_base + m * 16 + (lane >> 4) * 4 + r;
                if (row < M) {
                    float v = acc[m][n][r] + bv;
                    if (RELU) v = fmaxf(v, 0.f);
                    C[(size_t)row * 256 + col] = f2bf(v);
                }
            }
        }
    }
}

// ---------------- pooling ----------------
__global__ void gstart_kernel(const int* __restrict__ bids, int* __restrict__ gstart,
                              int n, int G) {
    int g = blockIdx.x * blockDim.x + threadIdx.x;
    if (g > G) return;
    if (g == G) { gstart[G] = n; return; }
    int lo = 0, hi = n;
    while (lo < hi) {
        int mid = (lo + hi) >> 1;
        if (bids[mid] < g) lo = mid + 1; else hi = mid;
    }
    gstart[g] = lo;
}

// grid (G, PSPLITS), 64 threads (1 wave). Vectorized row loads, f32 regs, atomic finish.
__global__ void pool_kernel(const ushort4* __restrict__ h4, const int* __restrict__ gstart,
                            float* __restrict__ pooled) {
    int g = blockIdx.x;
    int split = blockIdx.y;
    int lane = threadIdx.x;   // 0..63
    int lo = gstart[g], hi = gstart[g + 1];
    int cnt = hi - lo;
    int chunk = (cnt + PSPLITS - 1) / PSPLITS;
    int s0 = lo + split * chunk;
    int s1 = min(s0 + chunk, hi);
    if (s0 >= s1) return;
    float ax = 0.f, ay = 0.f, az = 0.f, aw = 0.f;
    for (int nd = s0; nd < s1; ++nd) {
        ushort4 v = h4[(size_t)nd * 64 + lane];
        ax += b2f(v.x); ay += b2f(v.y); az += b2f(v.z); aw += b2f(v.w);
    }
    float* p = &pooled[(size_t)g * DIM + lane * 4];
    atomicAdd(p + 0, ax);
    atomicAdd(p + 1, ay);
    atomicAdd(p + 2, az);
    atomicAdd(p + 3, aw);
}

__global__ void out_kernel(const float* __restrict__ pooled, const float* __restrict__ Wout,
                           const float* __restrict__ bout, float* __restrict__ out) {
    __shared__ float p[DIM];
    int g = blockIdx.x;
    for (int d = threadIdx.x; d < DIM; d += blockDim.x) p[d] = pooled[(size_t)g * DIM + d];
    __syncthreads();
    int o = threadIdx.x;
    if (o < DOUT) {
        float acc = bout[o];
        for (int d = 0; d < DIM; ++d) acc += p[d] * Wout[(size_t)d * DOUT + o];
        out[(size_t)g * DOUT + o] = acc;
    }
}

// ---------------- launch ----------------
extern "C" void kernel_launch(void* const* d_in, const int* in_sizes, int n_in,
                              void* d_out, int out_size, void* d_ws, size_t ws_size,
                              hipStream_t stream) {
    const float* x    = (const float*)d_in[0];
    const int*   esrc = (const int*)d_in[1];
    const int*   edst = (const int*)d_in[2];
    const int*   bids = (const int*)d_in[3];
    const float* W1   = (const float*)d_in[4];
    const float* b1   = (const float*)d_in[5];
    const float* W2   = (const float*)d_in[6];
    const float* b2   = (const float*)d_in[7];
    const float* Wout = (const float*)d_in[8];
    const float* bout = (const float*)d_in[9];

    const int N = in_sizes[3];             // 20000
    const int E = in_sizes[1];             // 320000
    const int L = in_sizes[5] / DIM;       // 4
    const int G = out_size / (DOUT + DIM); // 128

    char* ws = (char*)d_ws;
    size_t off = 0;
    auto carve = [&](size_t bytes) -> char* {
        char* p = ws + off;
        off = (off + bytes + 255) & ~(size_t)255;
        return p;
    };
    int* row_ptr = (int*)carve((size_t)(N + 1) * sizeof(int));
    int* cursor  = (int*)carve((size_t)N * sizeof(int));
    int* perm    = (int*)carve((size_t)E * sizeof(int));
    int* gstart  = (int*)carve((size_t)(G + 1) * sizeof(int));
    unsigned short* h   = (unsigned short*)carve((size_t)N * DIM * 2);
    unsigned short* z   = (unsigned short*)carve((size_t)N * DIM * 2);
    unsigned short* t   = (unsigned short*)carve((size_t)N * DIM * 2);
    unsigned short* wt1 = (unsigned short*)carve((size_t)L * DIM * DIM * 2);
    unsigned short* wt2 = (unsigned short*)carve((size_t)L * DIM * DIM * 2);
    (void)ws_size;

    // h = bf16(x)
    cvt_f32_bf16<<<2048, 256, 0, stream>>>((const float4*)x, (ushort4*)h, N * (DIM / 4));

    // CSR build (cursor doubles as degree scratch)
    hipMemsetAsync(cursor, 0, (size_t)N * sizeof(int), stream);
    hist_kernel<<<(E + 255) / 256, 256, 0, stream>>>(edst, cursor, E);
    scan_kernel<<<1, 256, 0, stream>>>(cursor, row_ptr, N);
    copy_i32<<<(N + 255) / 256, 256, 0, stream>>>(row_ptr, cursor, N);
    scatter_kernel<<<(E + 255) / 256, 256, 0, stream>>>(esrc, edst, cursor, perm, E);

    // Wt = bf16(W^T) for both MLP weight sets
    {
        dim3 tgrid(DIM / 32, DIM / 32, L);
        dim3 tblk(32, 8);
        transpose_w<<<tgrid, tblk, 0, stream>>>(W1, wt1);
        transpose_w<<<tgrid, tblk, 0, stream>>>(W2, wt2);
    }

    dim3 ggrid((N + 127) / 128, 4);
    for (int l = 0; l < L; ++l) {
        agg_kernel<<<(N + 3) / 4, 256, 0, stream>>>((const ushort4*)h, row_ptr, perm,
                                                    (ushort4*)z, N);
        mfma_gemm<true><<<ggrid, 256, 0, stream>>>(
            z, wt1 + (size_t)l * DIM * DIM, b1 + (size_t)l * DIM, t, N);
        if (l < L - 1)
            mfma_gemm<true><<<ggrid, 256, 0, stream>>>(
                t, wt2 + (size_t)l * DIM * DIM, b2 + (size_t)l * DIM, h, N);
        else
            mfma_gemm<false><<<ggrid, 256, 0, stream>>>(
                t, wt2 + (size_t)l * DIM * DIM, b2 + (size_t)l * DIM, h, N);
    }

    float* outp   = (float*)d_out;
    float* pooled = outp + (size_t)G * DOUT;
    // zero pooled (we accumulate into it with atomics)
    hipMemsetAsync(pooled, 0, (size_t)G * DIM * sizeof(float), stream);
    gstart_kernel<<<1, 256, 0, stream>>>(bids, gstart, N, G);
    {
        dim3 pgrid(G, PSPLITS);
        pool_kernel<<<pgrid, 64, 0, stream>>>((const ushort4*)h, gstart, pooled);
    }
    out_kernel<<<G, 64, 0, stream>>>(pooled, Wout, bout, outp);
}

// Round 4
// 330.490 us; speedup vs baseline: 2.0317x; 1.1661x over previous
//
#include <hip/hip_runtime.h>

#define DIM 256
#define DOUT 64
#define PSPLITS 16

typedef short bf16x8 __attribute__((ext_vector_type(8)));
typedef float f32x4 __attribute__((ext_vector_type(4)));
typedef unsigned short u16x8 __attribute__((ext_vector_type(8)));

// ---- bf16 helpers (bit-level, RNE) ----
static __device__ __forceinline__ float b2f(unsigned short u) {
    return __uint_as_float(((unsigned)u) << 16);
}
static __device__ __forceinline__ unsigned short f2bf(float f) {
    unsigned u = __float_as_uint(f);
    unsigned r = (u + 0x7fffu + ((u >> 16) & 1u)) >> 16;
    return (unsigned short)r;
}

// ---------------- convert x (f32) -> h (bf16) ----------------
__global__ void cvt_f32_bf16(const float4* __restrict__ src, ushort4* __restrict__ dst, int n4) {
    int i = blockIdx.x * blockDim.x + threadIdx.x;
    int stride = gridDim.x * blockDim.x;
    for (; i < n4; i += stride) {
        float4 v = src[i];
        ushort4 o;
        o.x = f2bf(v.x); o.y = f2bf(v.y); o.z = f2bf(v.z); o.w = f2bf(v.w);
        dst[i] = o;
    }
}

__global__ void copy_i32(const int* __restrict__ src, int* __restrict__ dst, int n) {
    int i = blockIdx.x * blockDim.x + threadIdx.x;
    if (i < n) dst[i] = src[i];
}

// ---------------- CSR build ----------------
__global__ void hist_kernel(const int* __restrict__ dst, int* __restrict__ deg, int E) {
    int i = blockIdx.x * blockDim.x + threadIdx.x;
    if (i < E) atomicAdd(&deg[dst[i]], 1);
}

__global__ void scan_kernel(const int* __restrict__ deg, int* __restrict__ row_ptr, int n) {
    __shared__ int sums[256];
    int t = threadIdx.x;
    int chunk = (n + 255) / 256;
    int lo = t * chunk;
    int hi = min(lo + chunk, n);
    int s = 0;
    for (int i = lo; i < hi; ++i) s += deg[i];
    sums[t] = s;
    __syncthreads();
    for (int off = 1; off < 256; off <<= 1) {
        int v = (t >= off) ? sums[t - off] : 0;
        __syncthreads();
        sums[t] += v;
        __syncthreads();
    }
    int excl = (t == 0) ? 0 : sums[t - 1];
    int run = excl;
    for (int i = lo; i < hi; ++i) { row_ptr[i] = run; run += deg[i]; }
    if (t == 255) row_ptr[n] = run;
}

__global__ void scatter_kernel(const int* __restrict__ src, const int* __restrict__ dst,
                               int* __restrict__ cursor, int* __restrict__ perm, int E) {
    int i = blockIdx.x * blockDim.x + threadIdx.x;
    if (i < E) {
        int d = dst[i];
        int p = atomicAdd(&cursor[d], 1);
        perm[p] = src[i];
    }
}

// ---------------- transpose + convert W [K][N] f32 -> Wt [N][K] bf16 ----------------
__global__ void transpose_w(const float* __restrict__ W, unsigned short* __restrict__ Wt) {
    __shared__ float tile[32][33];
    int l = blockIdx.z;
    int k0 = blockIdx.x * 32, n0 = blockIdx.y * 32;
    const float* Wl = W + (size_t)l * DIM * DIM;
    unsigned short* Wtl = Wt + (size_t)l * DIM * DIM;
    int tx = threadIdx.x, ty = threadIdx.y;
    for (int i = ty; i < 32; i += 8)
        tile[i][tx] = Wl[(size_t)(k0 + i) * DIM + n0 + tx];
    __syncthreads();
    for (int i = ty; i < 32; i += 8)
        Wtl[(size_t)(n0 + i) * DIM + k0 + tx] = f2bf(tile[tx][i]);
}

// ---------------- aggregation (bf16): z = h + sum_{e: dst=n} h[src[e]] ----------------
__global__ void agg_kernel(const ushort4* __restrict__ h4, const int* __restrict__ row_ptr,
                           const int* __restrict__ perm, ushort4* __restrict__ z4, int n) {
    int wave = threadIdx.x >> 6;
    int lane = threadIdx.x & 63;
    int node = blockIdx.x * 4 + wave;
    if (node >= n) return;
    size_t base = (size_t)node * 64 + lane;
    ushort4 hv = h4[base];
    float ax = b2f(hv.x), ay = b2f(hv.y), az = b2f(hv.z), aw = b2f(hv.w);
    int lo = row_ptr[node], hi = row_ptr[node + 1];
    int e = lo;
    for (; e + 4 <= hi; e += 4) {
        int s0 = perm[e], s1 = perm[e + 1], s2 = perm[e + 2], s3 = perm[e + 3];
        ushort4 v0 = h4[(size_t)s0 * 64 + lane];
        ushort4 v1 = h4[(size_t)s1 * 64 + lane];
        ushort4 v2 = h4[(size_t)s2 * 64 + lane];
        ushort4 v3 = h4[(size_t)s3 * 64 + lane];
        ax += b2f(v0.x) + b2f(v1.x) + b2f(v2.x) + b2f(v3.x);
        ay += b2f(v0.y) + b2f(v1.y) + b2f(v2.y) + b2f(v3.y);
        az += b2f(v0.z) + b2f(v1.z) + b2f(v2.z) + b2f(v3.z);
        aw += b2f(v0.w) + b2f(v1.w) + b2f(v2.w) + b2f(v3.w);
    }
    for (; e < hi; ++e) {
        int s0 = perm[e];
        ushort4 v0 = h4[(size_t)s0 * 64 + lane];
        ax += b2f(v0.x); ay += b2f(v0.y); az += b2f(v0.z); aw += b2f(v0.w);
    }
    ushort4 o;
    o.x = f2bf(ax); o.y = f2bf(ay); o.z = f2bf(az); o.w = f2bf(aw);
    z4[base] = o;
}

// ---------------- bf16 MFMA GEMM with LDS-staged B-tile ----------------
// Block: BM=128 rows x BN=64 cols, 4 waves; wave w = rows [w*32, w*32+32), all 64 cols.
// B-tile (64 cols x 256 K bf16 = 32 KB) staged in LDS with XOR swizzle
// (byte ^= (col&7)<<4) so frag ds_read_b128 is ~conflict-free.
template <bool RELU>
__global__ __launch_bounds__(256) void mfma_gemm(const unsigned short* __restrict__ A,
                                                 const unsigned short* __restrict__ Bt,
                                                 const float* __restrict__ bias,
                                                 unsigned short* __restrict__ C, int M) {
    __shared__ unsigned short Bs[64 * 256];   // [col][k] swizzled, 32 KB
    const int tid = threadIdx.x;
    const int wave = tid >> 6;
    const int lane = tid & 63;
    const int l15 = lane & 15;
    const int lk8 = (lane >> 4) * 8;          // 0,8,16,24 (k elems)
    const int m_base = blockIdx.x * 128 + wave * 32;
    const int n_blk = blockIdx.y * 64;

    // ---- stage B-tile: thread t loads col=t>>2, 128B segment seg=t&3 ----
    {
        const int col = tid >> 2;
        const int seg = tid & 3;
        const unsigned short* gsrc = &Bt[(size_t)(n_blk + col) * 256 + seg * 64];
        char* lbase = (char*)Bs + col * 512;
        const int sw = (col & 7) << 4;
#pragma unroll
        for (int j = 0; j < 8; ++j) {
            int kbyte = seg * 128 + j * 16;
            *reinterpret_cast<u16x8*>(lbase + (kbyte ^ sw)) =
                *reinterpret_cast<const u16x8*>((const char*)gsrc + j * 16);
        }
    }
    __syncthreads();

    f32x4 acc[2][4] = {};

#pragma unroll
    for (int kb = 0; kb < 256; kb += 32) {
        bf16x8 a[2], b[4];
#pragma unroll
        for (int m = 0; m < 2; ++m) {
            int r = m_base + m * 16 + l15;
            r = min(r, M - 1);
            a[m] = *reinterpret_cast<const bf16x8*>(&A[(size_t)r * 256 + kb + lk8]);
        }
#pragma unroll
        for (int n = 0; n < 4; ++n) {
            int col = n * 16 + l15;
            int kbyte = (kb + lk8) * 2;
            b[n] = *reinterpret_cast<const bf16x8*>(
                (const char*)Bs + col * 512 + (kbyte ^ ((col & 7) << 4)));
        }
#pragma unroll
        for (int m = 0; m < 2; ++m)
#pragma unroll
            for (int n = 0; n < 4; ++n)
                acc[m][n] = __builtin_amdgcn_mfma_f32_16x16x32_bf16(a[m], b[n], acc[m][n], 0, 0, 0);
    }

    // C/D layout: col = lane&15, row = (lane>>4)*4 + reg
#pragma unroll
    for (int n = 0; n < 4; ++n) {
        int col = n_blk + n * 16 + l15;
        float bv = bias[col];
#pragma unroll
        for (int m = 0; m < 2; ++m) {
#pragma unroll
            for (int r = 0; r < 4; ++r) {
                int row = m_base + m * 16 + (lane >> 4) * 4 + r;
                if (row < M) {
                    float v = acc[m][n][r] + bv;
                    if (RELU) v = fmaxf(v, 0.f);
                    C[(size_t)row * 256 + col] = f2bf(v);
                }
            }
        }
    }
}

// ---------------- pooling ----------------
__global__ void gstart_kernel(const int* __restrict__ bids, int* __restrict__ gstart,
                              int n, int G) {
    int g = blockIdx.x * blockDim.x + threadIdx.x;
    if (g > G) return;
    if (g == G) { gstart[G] = n; return; }
    int lo = 0, hi = n;
    while (lo < hi) {
        int mid = (lo + hi) >> 1;
        if (bids[mid] < g) lo = mid + 1; else hi = mid;
    }
    gstart[g] = lo;
}

__global__ void pool_kernel(const ushort4* __restrict__ h4, const int* __restrict__ gstart,
                            float* __restrict__ pooled) {
    int g = blockIdx.x;
    int split = blockIdx.y;
    int lane = threadIdx.x;   // 0..63
    int lo = gstart[g], hi = gstart[g + 1];
    int cnt = hi - lo;
    int chunk = (cnt + PSPLITS - 1) / PSPLITS;
    int s0 = lo + split * chunk;
    int s1 = min(s0 + chunk, hi);
    if (s0 >= s1) return;
    float ax = 0.f, ay = 0.f, az = 0.f, aw = 0.f;
    for (int nd = s0; nd < s1; ++nd) {
        ushort4 v = h4[(size_t)nd * 64 + lane];
        ax += b2f(v.x); ay += b2f(v.y); az += b2f(v.z); aw += b2f(v.w);
    }
    float* p = &pooled[(size_t)g * DIM + lane * 4];
    atomicAdd(p + 0, ax);
    atomicAdd(p + 1, ay);
    atomicAdd(p + 2, az);
    atomicAdd(p + 3, aw);
}

__global__ void out_kernel(const float* __restrict__ pooled, const float* __restrict__ Wout,
                           const float* __restrict__ bout, float* __restrict__ out) {
    __shared__ float p[DIM];
    int g = blockIdx.x;
    for (int d = threadIdx.x; d < DIM; d += blockDim.x) p[d] = pooled[(size_t)g * DIM + d];
    __syncthreads();
    int o = threadIdx.x;
    if (o < DOUT) {
        float acc = bout[o];
        for (int d = 0; d < DIM; ++d) acc += p[d] * Wout[(size_t)d * DOUT + o];
        out[(size_t)g * DOUT + o] = acc;
    }
}

// ---------------- launch ----------------
extern "C" void kernel_launch(void* const* d_in, const int* in_sizes, int n_in,
                              void* d_out, int out_size, void* d_ws, size_t ws_size,
                              hipStream_t stream) {
    const float* x    = (const float*)d_in[0];
    const int*   esrc = (const int*)d_in[1];
    const int*   edst = (const int*)d_in[2];
    const int*   bids = (const int*)d_in[3];
    const float* W1   = (const float*)d_in[4];
    const float* b1   = (const float*)d_in[5];
    const float* W2   = (const float*)d_in[6];
    const float* b2   = (const float*)d_in[7];
    const float* Wout = (const float*)d_in[8];
    const float* bout = (const float*)d_in[9];

    const int N = in_sizes[3];             // 20000
    const int E = in_sizes[1];             // 320000
    const int L = in_sizes[5] / DIM;       // 4
    const int G = out_size / (DOUT + DIM); // 128

    char* ws = (char*)d_ws;
    size_t off = 0;
    auto carve = [&](size_t bytes) -> char* {
        char* p = ws + off;
        off = (off + bytes + 255) & ~(size_t)255;
        return p;
    };
    int* row_ptr = (int*)carve((size_t)(N + 1) * sizeof(int));
    int* cursor  = (int*)carve((size_t)N * sizeof(int));
    int* perm    = (int*)carve((size_t)E * sizeof(int));
    int* gstart  = (int*)carve((size_t)(G + 1) * sizeof(int));
    unsigned short* h   = (unsigned short*)carve((size_t)N * DIM * 2);
    unsigned short* z   = (unsigned short*)carve((size_t)N * DIM * 2);
    unsigned short* t   = (unsigned short*)carve((size_t)N * DIM * 2);
    unsigned short* wt1 = (unsigned short*)carve((size_t)L * DIM * DIM * 2);
    unsigned short* wt2 = (unsigned short*)carve((size_t)L * DIM * DIM * 2);
    (void)ws_size;

    // h = bf16(x)
    cvt_f32_bf16<<<2048, 256, 0, stream>>>((const float4*)x, (ushort4*)h, N * (DIM / 4));

    // CSR build (cursor doubles as degree scratch)
    hipMemsetAsync(cursor, 0, (size_t)N * sizeof(int), stream);
    hist_kernel<<<(E + 255) / 256, 256, 0, stream>>>(edst, cursor, E);
    scan_kernel<<<1, 256, 0, stream>>>(cursor, row_ptr, N);
    copy_i32<<<(N + 255) / 256, 256, 0, stream>>>(row_ptr, cursor, N);
    scatter_kernel<<<(E + 255) / 256, 256, 0, stream>>>(esrc, edst, cursor, perm, E);

    // Wt = bf16(W^T) for both MLP weight sets
    {
        dim3 tgrid(DIM / 32, DIM / 32, L);
        dim3 tblk(32, 8);
        transpose_w<<<tgrid, tblk, 0, stream>>>(W1, wt1);
        transpose_w<<<tgrid, tblk, 0, stream>>>(W2, wt2);
    }

    dim3 ggrid((N + 127) / 128, 4);
    for (int l = 0; l < L; ++l) {
        agg_kernel<<<(N + 3) / 4, 256, 0, stream>>>((const ushort4*)h, row_ptr, perm,
                                                    (ushort4*)z, N);
        mfma_gemm<true><<<ggrid, 256, 0, stream>>>(
            z, wt1 + (size_t)l * DIM * DIM, b1 + (size_t)l * DIM, t, N);
        if (l < L - 1)
            mfma_gemm<true><<<ggrid, 256, 0, stream>>>(
                t, wt2 + (size_t)l * DIM * DIM, b2 + (size_t)l * DIM, h, N);
        else
            mfma_gemm<false><<<ggrid, 256, 0, stream>>>(
                t, wt2 + (size_t)l * DIM * DIM, b2 + (size_t)l * DIM, h, N);
    }

    float* outp   = (float*)d_out;
    float* pooled = outp + (size_t)G * DOUT;
    hipMemsetAsync(pooled, 0, (size_t)G * DIM * sizeof(float), stream);
    gstart_kernel<<<1, 256, 0, stream>>>(bids, gstart, N, G);
    {
        dim3 pgrid(G, PSPLITS);
        pool_kernel<<<pgrid, 64, 0, stream>>>((const ushort4*)h, gstart, pooled);
    }
    out_kernel<<<G, 64, 0, stream>>>(pooled, Wout, bout, outp);
}